// Round 5
// baseline (159.335 us; speedup 1.0000x reference)
//
#include <hip/hip_runtime.h>

#define N_TOTAL 16384
#define HALF    8192
#define FEAT    128
#define MARGIN  0.3f
#define NBINS   1024   // NUM_IDS=1000 <= 1024

typedef __attribute__((ext_vector_type(8))) short  short8v;   // 8 x bf16 (4 VGPRs)
typedef __attribute__((ext_vector_type(4))) float  float4v;   // 4 x f32 acc

__device__ __forceinline__ unsigned short f32_to_bf16_rne(float f) {
    unsigned u = __float_as_uint(f);
    u += 0x7FFFu + ((u >> 16) & 1u);
    return (unsigned short)(u >> 16);
}

// ---- DPP cross-lane min/max within 16-lane rows (VALU pipe, not DS) ------
template<int CTRL>
__device__ __forceinline__ float dpp_mov_f(float x) {
    return __int_as_float(__builtin_amdgcn_update_dpp(
        0, __float_as_int(x), CTRL, 0xF, 0xF, true));
}
__device__ __forceinline__ float rowmin16(float x) {
    x = fminf(x, dpp_mov_f<0xB1>(x));    // quad_perm(1,0,3,2)  xor1
    x = fminf(x, dpp_mov_f<0x4E>(x));    // quad_perm(2,3,0,1)  xor2
    x = fminf(x, dpp_mov_f<0x141>(x));   // ROW_HALF_MIRROR     pairs across quads
    x = fminf(x, dpp_mov_f<0x140>(x));   // ROW_MIRROR          pairs across octs
    return x;
}
__device__ __forceinline__ float rowmax16(float x) {
    x = fmaxf(x, dpp_mov_f<0xB1>(x));
    x = fmaxf(x, dpp_mov_f<0x4E>(x));
    x = fmaxf(x, dpp_mov_f<0x141>(x));
    x = fmaxf(x, dpp_mov_f<0x140>(x));
    return x;
}

// ---------------------------------------------------------------------------
// histscan: 2 blocks x 1024 (one per modality half). LDS histogram of labels
// + LDS scan -> cursor (bucket starts). Block 0 also zeroes accF/accI/ticket.
// ---------------------------------------------------------------------------
__global__ __launch_bounds__(1024) void histscan_kernel(
        const int* __restrict__ targets, int* __restrict__ cursor,
        int* __restrict__ accs /* [accF, accI, ticket] */) {
    __shared__ int lhist[NBINS];
    const int h = blockIdx.x;                       // half 0/1
    const int t = threadIdx.x;                      // 0..1023
    lhist[t] = 0;
    __syncthreads();
    const int* tg = targets + (h << 13);
    #pragma unroll
    for (int k = 0; k < 8; ++k)
        atomicAdd(&lhist[tg[k * 1024 + t]], 1);
    __syncthreads();
    const int lane = t & 63, wave = t >> 6;         // 16 waves
    int x = lhist[t];
    const int orig = x;
    #pragma unroll
    for (int m = 1; m < 64; m <<= 1) {              // inclusive wave scan
        int v = __shfl_up(x, m, 64);
        if (lane >= m) x += v;
    }
    __shared__ int wsum[16];
    if (lane == 63) wsum[wave] = x;
    __syncthreads();
    if (t == 0) {
        int s = 0;
        for (int w = 0; w < 16; ++w) { int v = wsum[w]; wsum[w] = s; s += v; }
        if (h == 0) { accs[0] = 0; accs[1] = 0; accs[2] = 0; }
    }
    __syncthreads();
    cursor[(h << 10) + t] = x - orig + wsum[wave];  // exclusive prefix
}

// ---------------------------------------------------------------------------
// prep: one wave per ORIGINAL row. Claims sorted slot via atomicAdd(cursor),
// converts fp32->bf16, computes bf16 row norm, writes Xb/sq/labs/sentinels.
// ---------------------------------------------------------------------------
__global__ __launch_bounds__(256) void prep_kernel(
        const float* __restrict__ X, const int* __restrict__ targets,
        int* __restrict__ cursor,
        unsigned* __restrict__ Xb, float* __restrict__ sq, int* __restrict__ labs,
        int* __restrict__ maxpos, int* __restrict__ minneg) {
    const int wave = threadIdx.x >> 6, lane = threadIdx.x & 63;
    const int src = blockIdx.x * 4 + wave;          // original row
    const int h   = src >> 13;
    const int lbl = targets[src];
    int dst;
    if (lane == 0)
        dst = (h << 13) + atomicAdd(&cursor[(h << 10) + lbl], 1);
    dst = __shfl(dst, 0, 64);
    const float2 xv = ((const float2*)(X + (size_t)src * FEAT))[lane];
    unsigned short h0 = f32_to_bf16_rne(xv.x);
    unsigned short h1 = f32_to_bf16_rne(xv.y);
    Xb[dst * 64 + lane] = (unsigned)h0 | ((unsigned)h1 << 16);
    float x0 = __uint_as_float((unsigned)h0 << 16);
    float x1 = __uint_as_float((unsigned)h1 << 16);
    float p = x0 * x0 + x1 * x1;
    #pragma unroll
    for (int m = 1; m < 64; m <<= 1) p += __shfl_xor(p, m, 64);
    if (lane == 0) {
        sq[dst]     = p;
        labs[dst]   = lbl;
        maxpos[dst] = (int)0xFF800000u;   // -inf
        minneg[dst] = 0x7F800000;         // +inf
    }
}

// ---------------------------------------------------------------------------
// main: NO LDS, NO barriers. 256 threads = 4 waves, each a 64x64 quadrant of
// a 128x128 tile. MFMA fragments loaded DIRECTLY global->VGPR (L2-resident
// 4 MB input; 16B/lane chunks, adjacent kk share 128B lines via L1).
// Fast path when label ranges of A-rows and B-cols are disjoint.
// ---------------------------------------------------------------------------
__global__ __launch_bounds__(256, 3) void cross_kernel(
        const unsigned short* __restrict__ Xb, const float* __restrict__ sq,
        const int* __restrict__ labs,
        int* __restrict__ maxpos, int* __restrict__ minneg) {
    const int bm = blockIdx.x, bn = blockIdx.y;
    const int t  = threadIdx.x;
    const int wave = t >> 6, lane = t & 63;
    const int q = lane >> 4, c = lane & 15;
    const int wr = (wave >> 1) * 64, wc = (wave & 1) * 64;

    // per-lane fragment base pointers (row*256B + q*16B); kk adds 64B steps
    const unsigned short* pA[4];
    const unsigned short* pB[4];
    #pragma unroll
    for (int ti = 0; ti < 4; ++ti)
        pA[ti] = Xb + (size_t)(bm * 128 + wr + ti * 16 + c) * FEAT + q * 8;
    #pragma unroll
    for (int tj = 0; tj < 4; ++tj)
        pB[tj] = Xb + (size_t)(HALF + bn * 128 + wc + tj * 16 + c) * FEAT + q * 8;

    float4v acc[4][4] = {};
    #pragma unroll
    for (int kk = 0; kk < 4; ++kk) {
        short8v af[4], bfr[4];
        #pragma unroll
        for (int ti = 0; ti < 4; ++ti)
            af[ti] = *(const short8v*)(pA[ti] + kk * 32);
        #pragma unroll
        for (int tj = 0; tj < 4; ++tj)
            bfr[tj] = *(const short8v*)(pB[tj] + kk * 32);
        #pragma unroll
        for (int ti = 0; ti < 4; ++ti)
            #pragma unroll
            for (int tj = 0; tj < 4; ++tj)
                acc[ti][tj] = __builtin_amdgcn_mfma_f32_16x16x32_bf16(
                    af[ti], bfr[tj], acc[ti][tj], 0, 0, 0);
    }

    // ---- epilogue: C layout col = lane&15 (=c), row = q*4 + reg
    const float NEG_INF = __int_as_float((int)0xFF800000u);
    const float POS_INF = __int_as_float(0x7F800000);

    const int aMin = labs[bm * 128], aMax = labs[bm * 128 + 127];
    const int bMn  = labs[HALF + bn * 128], bMx = labs[HALF + bn * 128 + 127];
    const bool overlap = (aMax >= bMn) && (bMx >= aMin);   // block-uniform

    float sA[16];
    #pragma unroll
    for (int ti = 0; ti < 4; ++ti)
        #pragma unroll
        for (int reg = 0; reg < 4; ++reg)
            sA[ti * 4 + reg] = sq[bm * 128 + wr + ti * 16 + q * 4 + reg];
    float sB[4];
    #pragma unroll
    for (int tj = 0; tj < 4; ++tj)
        sB[tj] = sq[HALF + bn * 128 + wc + tj * 16 + c];

    float rmin[16], cmin[4];
    #pragma unroll
    for (int i = 0; i < 16; ++i) rmin[i] = POS_INF;
    #pragma unroll
    for (int j = 0; j < 4; ++j)  cmin[j] = POS_INF;

    if (!overlap) {
        // ---- fast path: every pair is a negative
        #pragma unroll
        for (int ti = 0; ti < 4; ++ti)
            #pragma unroll
            for (int tj = 0; tj < 4; ++tj)
                #pragma unroll
                for (int reg = 0; reg < 4; ++reg) {
                    int ri = ti * 4 + reg;
                    float d2 = fmaf(acc[ti][tj][reg], -2.0f, sA[ri] + sB[tj]);
                    rmin[ri] = fminf(rmin[ri], d2);
                    cmin[tj] = fminf(cmin[tj], d2);
                }
        #pragma unroll
        for (int i = 0; i < 16; ++i) rmin[i] = rowmin16(rmin[i]);  // DPP, VALU pipe
        if (c == 0) {
            #pragma unroll
            for (int ti = 0; ti < 4; ++ti)
                #pragma unroll
                for (int reg = 0; reg < 4; ++reg)
                    atomicMin(&minneg[bm * 128 + wr + ti * 16 + q * 4 + reg],
                              __float_as_int(rmin[ti * 4 + reg]));
        }
        #pragma unroll
        for (int m = 16; m <= 32; m <<= 1)
            #pragma unroll
            for (int j = 0; j < 4; ++j)
                cmin[j] = fminf(cmin[j], __shfl_xor(cmin[j], m, 64));
        if (q == 0) {
            #pragma unroll
            for (int tj = 0; tj < 4; ++tj)
                atomicMin(&minneg[HALF + bn * 128 + wc + tj * 16 + c],
                          __float_as_int(cmin[tj]));
        }
    } else {
        // ---- slow path: labels may match
        float rmax[16], cmax[4];
        #pragma unroll
        for (int i = 0; i < 16; ++i) rmax[i] = NEG_INF;
        #pragma unroll
        for (int j = 0; j < 4; ++j)  cmax[j] = NEG_INF;

        int tA[16];
        #pragma unroll
        for (int ti = 0; ti < 4; ++ti)
            #pragma unroll
            for (int reg = 0; reg < 4; ++reg)
                tA[ti * 4 + reg] = labs[bm * 128 + wr + ti * 16 + q * 4 + reg];
        int tB[4];
        #pragma unroll
        for (int tj = 0; tj < 4; ++tj)
            tB[tj] = labs[HALF + bn * 128 + wc + tj * 16 + c];

        #pragma unroll
        for (int ti = 0; ti < 4; ++ti)
            #pragma unroll
            for (int tj = 0; tj < 4; ++tj) {
                #pragma unroll
                for (int reg = 0; reg < 4; ++reg) {
                    int ri = ti * 4 + reg;
                    float d2 = fmaf(acc[ti][tj][reg], -2.0f, sA[ri] + sB[tj]);
                    bool same = (tA[ri] == tB[tj]);
                    float posc = same ? d2 : NEG_INF;
                    float negc = same ? POS_INF : d2;
                    rmax[ri] = fmaxf(rmax[ri], posc);
                    cmax[tj] = fmaxf(cmax[tj], posc);
                    rmin[ri] = fminf(rmin[ri], negc);
                    cmin[tj] = fminf(cmin[tj], negc);
                }
            }
        #pragma unroll
        for (int i = 0; i < 16; ++i) {
            rmax[i] = rowmax16(rmax[i]);
            rmin[i] = rowmin16(rmin[i]);
        }
        if (c == 0) {
            #pragma unroll
            for (int ti = 0; ti < 4; ++ti)
                #pragma unroll
                for (int reg = 0; reg < 4; ++reg) {
                    int gi = bm * 128 + wr + ti * 16 + q * 4 + reg;
                    atomicMax(&maxpos[gi], __float_as_int(rmax[ti * 4 + reg]));
                    atomicMin(&minneg[gi], __float_as_int(rmin[ti * 4 + reg]));
                }
        }
        #pragma unroll
        for (int m = 16; m <= 32; m <<= 1)
            #pragma unroll
            for (int j = 0; j < 4; ++j) {
                cmax[j] = fmaxf(cmax[j], __shfl_xor(cmax[j], m, 64));
                cmin[j] = fminf(cmin[j], __shfl_xor(cmin[j], m, 64));
            }
        if (q == 0) {
            #pragma unroll
            for (int tj = 0; tj < 4; ++tj) {
                int gj = HALF + bn * 128 + wc + tj * 16 + c;
                atomicMax(&maxpos[gj], __float_as_int(cmax[tj]));
                atomicMin(&minneg[gj], __float_as_int(cmin[tj]));
            }
        }
    }
}

// ---------------------------------------------------------------------------
// final: per-row loss terms -> global accumulators; LAST block (ticket)
// writes d_out.
// ---------------------------------------------------------------------------
__global__ __launch_bounds__(256) void final_kernel(
        const int* __restrict__ maxpos, const int* __restrict__ minneg,
        int* __restrict__ accs /* [accF, accI, ticket] */,
        float* __restrict__ out) {
    const int i = blockIdx.x * 256 + threadIdx.x;  // 64 blocks x 256 = 16384
    const int t = threadIdx.x;
    float* accF  = (float*)&accs[0];
    int*   accI  = &accs[1];
    int*   tick  = &accs[2];
    float ap = sqrtf(fmaxf(__int_as_float(maxpos[i]), 1e-12f));
    float an = sqrtf(fmaxf(__int_as_float(minneg[i]), 1e-12f));
    float term = fmaxf(ap - an + MARGIN, 0.0f);
    int cnt = (an >= ap) ? 1 : 0;
    #pragma unroll
    for (int m = 1; m < 64; m <<= 1) {
        term += __shfl_xor(term, m, 64);
        cnt  += __shfl_xor(cnt, m, 64);
    }
    __shared__ float sf[4];
    __shared__ int   si[4];
    if ((t & 63) == 0) { sf[t >> 6] = term; si[t >> 6] = cnt; }
    __syncthreads();
    if (t == 0) {
        atomicAdd(accF, sf[0] + sf[1] + sf[2] + sf[3]);
        atomicAdd(accI, si[0] + si[1] + si[2] + si[3]);
        __threadfence();
        int old = atomicAdd(tick, 1);
        if (old == gridDim.x - 1) {                // last block: all adds visible
            __threadfence();
            float S = atomicAdd(accF, 0.0f);
            int   C = atomicAdd(accI, 0);
            out[0] = S / (float)N_TOTAL;
            out[1] = (float)C;
        }
    }
}

extern "C" void kernel_launch(void* const* d_in, const int* in_sizes, int n_in,
                              void* d_out, int out_size, void* d_ws, size_t ws_size,
                              hipStream_t stream) {
    const float* X       = (const float*)d_in[0];   // [16384,128] fp32
    const int*   targets = (const int*)d_in[1];     // [16384] int32
    float* out = (float*)d_out;                     // [2]: loss, correct

    char* ws = (char*)d_ws;
    const size_t XB_BYTES = (size_t)N_TOTAL * FEAT * 2;              // 4 MB
    unsigned* Xb  = (unsigned*)ws;
    float* sq     = (float*)(ws + XB_BYTES);                         // 64 KB
    int* maxpos   = (int*)(ws + XB_BYTES + 1 * 65536);               // 64 KB
    int* minneg   = (int*)(ws + XB_BYTES + 2 * 65536);               // 64 KB
    int* labs     = (int*)(ws + XB_BYTES + 3 * 65536);               // 64 KB
    int* cursor   = (int*)(ws + XB_BYTES + 4 * 65536);               // 8 KB (2x1024)
    int* accs     = cursor + 2 * NBINS;                              // 12 B

    histscan_kernel<<<2, 1024, 0, stream>>>(targets, cursor, accs);
    prep_kernel    <<<4096, 256, 0, stream>>>(X, targets, cursor, Xb, sq, labs,
                                              maxpos, minneg);
    cross_kernel   <<<dim3(64, 64), 256, 0, stream>>>(
        (const unsigned short*)Xb, sq, labs, maxpos, minneg);
    final_kernel   <<<64, 256, 0, stream>>>(maxpos, minneg, accs, out);
}